// Round 12
// baseline (37.617 us; speedup 1.0000x reference)
//
#include <hip/hip_runtime.h>
#include <stdint.h>

// DecoupledMoE via bf16 MFMA, R12.
// R11 post-mortem: counted-vmcnt barrier = NULL (37.5us); FETCH=50.7MB shows
// out-stores evict x from L3 (x alone is 103MB; half refetched per dispatch).
// R12 single change: NON-TEMPORAL stores (nt hint) -> out bypasses L2/L3
// allocation, x stays L3-resident, HBM fetch ~0, write-stream bound.

typedef __bf16 bf16x8 __attribute__((ext_vector_type(8)));
typedef float  f32x16 __attribute__((ext_vector_type(16)));

#define HW    3136
#define CIN   64
#define COUT  64
#define PXB   64               // pixels per tile
#define NT    7                // tiles per block
#define BPX   (PXB * NT)       // 448 px per block; 7 blocks cover 3136 exactly

__device__ __forceinline__ void g2lds16(const float* g, float* lds_base) {
    // LDS dest = wave-uniform base + lane*16; global src per-lane.
    __builtin_amdgcn_global_load_lds(
        (const __attribute__((address_space(1))) void*)g,
        (__attribute__((address_space(3))) void*)lds_base,
        16, 0, 0);
}

__global__ __launch_bounds__(256, 4) void moe_mfma(
    const float* __restrict__ x,
    const float* __restrict__ weights,
    const int*   __restrict__ indices,
    const float* __restrict__ W_shared,
    const float* __restrict__ b_shared,
    const float* __restrict__ W_routed,
    const float* __restrict__ b_routed,
    float* __restrict__ out)
{
    __shared__ __attribute__((aligned(16))) float  xl[2][CIN * PXB]; // 2x16KB
    __shared__ __attribute__((aligned(16))) __bf16 wl[COUT * CIN];   // 8KB swizzled

    const int bs      = blockIdx.y;
    const int px_base = blockIdx.x * BPX;

    const int tid  = threadIdx.x;
    const int wave = tid >> 6;
    const int lane = tid & 63;
    const int l5   = lane >> 5;
    const int l31  = lane & 31;

    const float wb = weights[bs];
    const int   e  = indices[bs];

    const float* __restrict__ xs = x   + (size_t)bs * CIN  * HW;
    float*       __restrict__ os = out + (size_t)bs * COUT * HW;

    // ---- coop W_eff: coalesced fp32 loads -> bf16 swizzled LDS ----
    {
        const float4* Ws4 = (const float4*)W_shared;
        const float4* Wr4 = (const float4*)(W_routed + (size_t)e * (COUT * CIN));
        #pragma unroll
        for (int it = 0; it < 4; ++it) {
            const int f4 = tid + it * 256;       // float4 index 0..1023
            float4 s = Ws4[f4], r = Wr4[f4];
            const int o = f4 >> 4;               // out-ch row (16 float4/row)
            const int k = (f4 & 15) * 4;         // col
            __bf16* dst = (__bf16*)((char*)wl +
                          ((((o * 64 + k) * 2)) ^ ((o & 7) << 4)));
            dst[0] = (__bf16)(s.x + wb * r.x);
            dst[1] = (__bf16)(s.y + wb * r.y);
            dst[2] = (__bf16)(s.z + wb * r.z);
            dst[3] = (__bf16)(s.w + wb * r.w);
        }
    }

    // ---- stage macro: wave w covers k-rows [16w,16w+16), 4 x 1KB instrs ----
    #define STAGE(BI, T) do {                                              \
        const float* xs_t = xs + px_base + (T) * PXB;                      \
        _Pragma("unroll")                                                  \
        for (int i_ = 0; i_ < 4; ++i_) {                                   \
            const int row_ = 16 * wave + 4 * i_;                           \
            g2lds16(xs_t + (size_t)(row_ + (lane >> 4)) * HW + 4 * (lane & 15), \
                    &xl[BI][row_ * PXB]);                                  \
        }                                                                  \
    } while (0)

    STAGE(0, 0);

    // ---- fused bias while loads are in flight ----
    const int ob = (wave >> 1) * 32;    // this wave's o-tile (0 or 32)
    f32x16 biasv;
    #pragma unroll
    for (int g = 0; g < 4; ++g) {
        const int o4 = ob + 8 * g + 4 * l5;
        float4 s = *(const float4*)(b_shared + o4);
        float4 r = *(const float4*)(b_routed + e * COUT + o4);
        biasv[4 * g + 0] = s.x + wb * r.x;
        biasv[4 * g + 1] = s.y + wb * r.y;
        biasv[4 * g + 2] = s.z + wb * r.z;
        biasv[4 * g + 3] = s.w + wb * r.w;
    }

    __syncthreads();   // full drain once: W_eff ds_writes + stage0

    // ---- A fragments from swizzled LDS: 4 x ds_read_b128 (once) ----
    bf16x8 afrag[4];
    {
        const int arow = ob + l31;
        #pragma unroll
        for (int ks = 0; ks < 4; ++ks) {
            const int byte = ((arow * 64 + 16 * ks + 8 * l5) * 2)
                             ^ ((arow & 7) << 4);
            afrag[ks] = *(const bf16x8*)((const char*)wl + byte);
        }
    }

    const int pxl = (wave & 1) * 32 + l31;   // wave = o-tile x px-half

    #pragma unroll 1
    for (int t = 0; t < NT; ++t) {
        const float* xb = xl[t & 1];

        // (1) ds_reads FIRST (before STAGE: no gload_lds/ds_read alias stall)
        float xf[4][8];
        #pragma unroll
        for (int ks = 0; ks < 4; ++ks)
            #pragma unroll
            for (int j = 0; j < 8; ++j)
                xf[ks][j] = xb[(16 * ks + 8 * l5 + j) * PXB + pxl];

        // (2) issue next tile's stage (4 gload_lds per wave, stays in flight)
        if (t + 1 < NT) STAGE((t + 1) & 1, t + 1);

        // (3) convert + MFMA
        f32x16 acc = biasv;
        #pragma unroll
        for (int ks = 0; ks < 4; ++ks) {
            bf16x8 bfr;
            #pragma unroll
            for (int j = 0; j < 8; ++j) bfr[j] = (__bf16)xf[ks][j];
            acc = __builtin_amdgcn_mfma_f32_32x32x16_bf16(afrag[ks], bfr, acc, 0, 0, 0);
        }

        // (4) NON-TEMPORAL stores: bypass L2/L3 allocation (out never re-read;
        //     keeps x L3-resident). Left in flight across the barrier.
        float* os_t = os + px_base + t * PXB;
        #pragma unroll
        for (int r = 0; r < 16; ++r) {
            const int row = ob + (r & 3) + 8 * (r >> 2) + 4 * l5;
            __builtin_nontemporal_store(acc[r], &os_t[(size_t)row * HW + pxl]);
        }

        // (5) counted wait: retire the 4 stage ops only (stores stay in flight)
        if (t + 1 < NT) {
            asm volatile("s_waitcnt vmcnt(16)" ::: "memory");
            __builtin_amdgcn_s_barrier();
            __builtin_amdgcn_sched_barrier(0);
        }
    }
}

extern "C" void kernel_launch(void* const* d_in, const int* in_sizes, int n_in,
                              void* d_out, int out_size, void* d_ws, size_t ws_size,
                              hipStream_t stream) {
    const float* x        = (const float*)d_in[0];
    const float* weights  = (const float*)d_in[1];
    const int*   indices  = (const int*)  d_in[2];
    const float* W_shared = (const float*)d_in[3];
    const float* b_shared = (const float*)d_in[4];
    const float* W_routed = (const float*)d_in[5];
    const float* b_routed = (const float*)d_in[6];
    float* out = (float*)d_out;

    // 7 px-groups x 128 samples = 896 blocks
    moe_mfma<<<dim3(7, 128), 256, 0, stream>>>(
        x, weights, indices, W_shared, b_shared, W_routed, b_routed, out);
}